// Round 16
// baseline (101.916 us; speedup 1.0000x reference)
//
#include <hip/hip_runtime.h>
#include <hip/hip_bf16.h>
#include <stdint.h>

#define G_ 4
#define N_ 4096
#define D_ 1024             // K in elements
#define BKE_ 128            // K-elements per tile = one 16x16x128 fp4 MFMA
#define BKB_ 64             // K-bytes per tile row (fp4 = 0.5 B/elem)
#define KT_ (D_ / BKE_)     // 8 K-tiles
#define ROWB_ (D_ / 2)      // 512 B per row in fp4 z-file
#define MAX_LOGIT_SCALE_F 4.605170185988091f
#define ZS4 48.0f           // pre-quantization scale; logits /= ZS4^2

typedef float f32x4 __attribute__((ext_vector_type(4)));
typedef int i32x4 __attribute__((ext_vector_type(4)));
typedef int i32x8 __attribute__((ext_vector_type(8)));

#define AS1 __attribute__((address_space(1)))
#define AS3 __attribute__((address_space(3)))

// ---------------------------------------------------------------------------
// Mask dtype detection (reference dtype bool; harness may store bytes or i32).
// ---------------------------------------------------------------------------
__device__ inline bool mask_is_bytes(const void* masks) {
  const unsigned char* b = (const unsigned char*)masks;
  return (b[1] | b[2] | b[3]) != 0;
}
__device__ inline float mask_val(const void* masks, int idx, bool as_bytes) {
  if (as_bytes) return ((const unsigned char*)masks)[idx] ? 1.0f : 0.0f;
  return ((const int*)masks)[idx] ? 1.0f : 0.0f;
}

// ---------------------------------------------------------------------------
// fp4 e2m1 quantize (nearest; grid 0,.5,1,1.5,2,3,4,6) -> 4-bit code.
// ---------------------------------------------------------------------------
__device__ inline unsigned int q_e2m1(float x) {
  const unsigned int s = (__float_as_uint(x) >> 31) << 3;
  const float a = fabsf(x);
  unsigned int c;
  if (a < 1.25f) {
    c = (a < 0.25f) ? 0u : (a < 0.75f) ? 1u : 2u;
  } else if (a < 2.5f) {
    c = (a < 1.75f) ? 3u : 4u;
  } else {
    c = (a < 3.5f) ? 5u : (a < 5.0f) ? 6u : 7u;
  }
  return s | c;
}

// ---------------------------------------------------------------------------
// Kernel 1 (R10-verified): L2-normalize rows -> fp4 e2m1 pre-swizzled
// z-file. WAVE-per-row: lane holds 16 contiguous elems, __shfl_xor reduce,
// one u64 store. Swizzle: byte b -> (b&~63)|((b&63)^(((row>>1)&3)<<4)).
// ---------------------------------------------------------------------------
__global__ __launch_bounds__(256) void norm_kernel(
    const float* __restrict__ merged, const float* __restrict__ orig,
    unsigned char* __restrict__ zq) {
  const int w = threadIdx.x >> 6;
  const int lane = threadIdx.x & 63;
  const int row = blockIdx.x * 4 + w;         // 0 .. 2*G*N-1
  const int GN = G_ * N_;
  const float* src = (row < GN) ? (merged + (size_t)row * D_)
                                : (orig + (size_t)(row - GN) * D_);
  float4 v[4];
  float ss = 0.0f;
#pragma unroll
  for (int c = 0; c < 4; ++c) {
    v[c] = *reinterpret_cast<const float4*>(src + lane * 16 + c * 4);
    ss += v[c].x * v[c].x + v[c].y * v[c].y + v[c].z * v[c].z + v[c].w * v[c].w;
  }
#pragma unroll
  for (int off = 32; off; off >>= 1) ss += __shfl_xor(ss, off, 64);
  const float inv = ZS4 / fmaxf(sqrtf(ss), 1e-12f);

  unsigned long long pk = 0ull;
#pragma unroll
  for (int c = 0; c < 4; ++c) {
    pk |= (unsigned long long)q_e2m1(v[c].x * inv) << (c * 16 + 0);
    pk |= (unsigned long long)q_e2m1(v[c].y * inv) << (c * 16 + 4);
    pk |= (unsigned long long)q_e2m1(v[c].z * inv) << (c * 16 + 8);
    pk |= (unsigned long long)q_e2m1(v[c].w * inv) << (c * 16 + 12);
  }
  const int p0 = lane * 8;
  const int swz = ((row >> 1) & 3) << 4;
  const int off = (p0 & ~63) | ((p0 & 63) ^ swz);
  *reinterpret_cast<unsigned long long*>(zq + (size_t)row * ROWB_ + off) = pk;
}

// ---------------------------------------------------------------------------
// Kernel 2: 128x128-tile MX-fp4 GEMM + fused SigLIP loss. R8/R11 structure
// (#pragma unroll 1 load-bearing; launch_bounds(256,4); R15 mask staging).
// R16: (a) persistent staging pointers advanced += BKB_ per K-iter (replaces
// per-iter address recompute); (b) 4-way lsum accumulators (break the
// 64-long serial FP-add chain).
// ---------------------------------------------------------------------------
__global__ __launch_bounds__(256, 4) void gemm_loss_kernel(
    const unsigned char* __restrict__ z1q, const unsigned char* __restrict__ z2q,
    const void* __restrict__ masks,
    const float* __restrict__ p_ls, const float* __restrict__ p_lb,
    float* __restrict__ partial) {
  // [buf][A 128x64 | B 128x64] = 2 * 16 KiB = 32 KiB exactly
  __shared__ __align__(16) unsigned char sh[2 * 16384];

  // 2D XCD-chunked swizzle: each XCD owns an 8x16 rect of a 32x32 tile grid.
  const int f   = blockIdx.x;          // 0..4095
  const int xcd = f & 7;
  const int u   = f >> 3;              // 0..511
  const int g   = u >> 7;              // 0..3
  const int q   = u & 127;             // 0..127
  const int ty  = (xcd >> 1) * 8 + (q >> 4);   // 0..31
  const int tx  = (xcd & 1) * 16 + (q & 15);   // 0..31
  const int tm = ty * 128;
  const int tn = tx * 128;

  const unsigned char* Abase = z1q + ((size_t)g * N_ + tm) * ROWB_;
  const unsigned char* Bbase = z2q + ((size_t)g * N_ + tn) * ROWB_;

  const int tid  = threadIdx.x;
  const int wave = tid >> 6;
  const int lane = tid & 63;
  const int wr = (wave >> 1) * 64;
  const int wc = (wave & 1) * 64;

  const int rlo  = lane & 15;
  const int kb0f = (lane >> 4) * 16;   // lane's 16-B (32-elem) K-chunk base

  f32x4 acc[4][4] = {};

  // hoisted loop-invariant swizzled LDS byte offsets (8 VGPR)
  int offA[4], offB[4];
#pragma unroll
  for (int i = 0; i < 4; ++i) {
    const int rowA = wr + i * 16 + rlo;
    offA[i] = rowA * BKB_ + (kb0f ^ (((rowA >> 1) & 3) << 4));
    const int rowB = wc + i * 16 + rlo;
    offB[i] = rowB * BKB_ + (kb0f ^ (((rowB >> 1) & 3) << 4));
  }

  // persistent staging pointers (advanced += BKB_ after each stage issue)
  const int gr0 = tid;                 // r=0: row gr/4, granule gr%4
  const int gr1 = 256 + tid;           // r=1
  const unsigned char* sa0 = Abase + (size_t)(gr0 >> 2) * ROWB_ + (gr0 & 3) * 16;
  const unsigned char* sa1 = Abase + (size_t)(gr1 >> 2) * ROWB_ + (gr1 & 3) * 16;
  const unsigned char* sb0 = Bbase + (size_t)(gr0 >> 2) * ROWB_ + (gr0 & 3) * 16;
  const unsigned char* sb1 = Bbase + (size_t)(gr1 >> 2) * ROWB_ + (gr1 & 3) * 16;
  const int wb = wave * 1024;

  // issue 4 global_load_lds from current pointers into buf, then advance.
  auto stage = [&](unsigned char* buf) {
    __builtin_amdgcn_global_load_lds((const AS1 void*)sa0,
                                     (AS3 void*)(buf + wb), 16, 0, 0);
    __builtin_amdgcn_global_load_lds((const AS1 void*)sa1,
                                     (AS3 void*)(buf + 4096 + wb), 16, 0, 0);
    __builtin_amdgcn_global_load_lds((const AS1 void*)sb0,
                                     (AS3 void*)(buf + 8192 + wb), 16, 0, 0);
    __builtin_amdgcn_global_load_lds((const AS1 void*)sb1,
                                     (AS3 void*)(buf + 12288 + wb), 16, 0, 0);
    sa0 += BKB_; sa1 += BKB_; sb0 += BKB_; sb1 += BKB_;
  };

  auto read_frag = [&](const unsigned char* S, int off) -> i32x8 {
    const i32x4 lo = *reinterpret_cast<const i32x4*>(S + off);
    // fp4 FMT (cbsz/blgp=4) reads only v[0:3]; high half left undef.
    return __builtin_shufflevector(lo, lo, 0, 1, 2, 3, -1, -1, -1, -1);
  };

#define MFMA_FP4(a, b, c) \
  __builtin_amdgcn_mfma_scale_f32_16x16x128_f8f6f4((a), (b), (c), 4, 4, 0, 127, 0, 127)

  stage(sh);
  __syncthreads();

#pragma unroll 1
  for (int kt = 0; kt < KT_; ++kt) {
    const unsigned char* bufR = sh + (kt & 1) * 16384;
    unsigned char* bufW = sh + ((kt + 1) & 1) * 16384;
    const unsigned char* sA = bufR;
    const unsigned char* sB = bufR + 8192;

    if (kt + 1 < KT_) stage(bufW);  // hides under this tile's MFMA

    i32x8 af[4];
#pragma unroll
    for (int i = 0; i < 4; ++i) af[i] = read_frag(sA, offA[i]);

#pragma unroll
    for (int j = 0; j < 4; ++j) {
      const i32x8 bfj = read_frag(sB, offB[j]);
#pragma unroll
      for (int i = 0; i < 4; ++i)
        acc[i][j] = MFMA_FP4(af[i], bfj, acc[i][j]);
    }
    __syncthreads();  // drains vmcnt (stage visible) + protects bufR
  }
#undef MFMA_FP4

  // ---- cooperative mask staging: 2 coalesced loads/thread -> LDS ----
  const bool as_bytes = mask_is_bytes(masks);
  const int mbase = g * N_;
  float* shmask = (float*)sh;  // 256 floats = 1 KB (tile reads all drained)
  {
    const int half = tid >> 7;          // 0: row masks, 1: col masks
    const int idx  = tid & 127;
    const int base = half ? (mbase + tn) : (mbase + tm);
    shmask[tid] = mask_val(masks, base + idx, as_bytes);
  }
  __syncthreads();

  // ---- fused loss epilogue (C/D layout shape-determined: m89/m127) ----
  const float scale = expf(fminf(p_ls[0], MAX_LOGIT_SCALE_F));
  const float sfac  = scale * (1.0f / (ZS4 * ZS4));
  const float lbias = p_lb[0];

  const int lr0 = wr + ((lane >> 4) << 2);  // local row base (+ i*16 + j)
  const int lc0 = wc + (lane & 15);         // local col base (+ fc*16)

  float mC[4];
#pragma unroll
  for (int fc = 0; fc < 4; ++fc) mC[fc] = shmask[128 + lc0 + fc * 16];

  float ls4[4] = {0.0f, 0.0f, 0.0f, 0.0f};  // 4 chains (break FP-add dep)
  const bool poly_ok = (scale + fabsf(lbias) <= 1.5f);
  // softplus(u) = 0.5u + P(u^2), P = ln2 + t/8 - t^2/192 + t^3/2880
  //   - 17 t^4/645120; |u| <= scale*1.3 + |bias| (Cauchy-Schwarz + fp4 slack)
  if (poly_ok && tm != tn) {
    // off-diagonal block (97% of blocks): no r==c possible, u = +v always.
#pragma unroll
    for (int i = 0; i < 4; ++i) {
#pragma unroll
      for (int j = 0; j < 4; ++j) {
        const float mR = shmask[lr0 + i * 16 + j];
#pragma unroll
        for (int fc = 0; fc < 4; ++fc) {
          const float v = acc[i][fc][j] * sfac + lbias;  // logit = u
          const float t = v * v;
          const float p = 0.69314718f +
              t * (0.125f +
              t * (-0.0052083335f +
              t * (0.00034722223f +
              t * (-2.6351686e-5f))));
          ls4[i] += mR * mC[fc] * (0.5f * v + p);
        }
      }
    }
  } else if (poly_ok) {
    // diagonal block: keep the r==c sign flip.
#pragma unroll
    for (int i = 0; i < 4; ++i) {
#pragma unroll
      for (int j = 0; j < 4; ++j) {
        const int lr = lr0 + i * 16 + j;
        const float mR = shmask[lr];
#pragma unroll
        for (int fc = 0; fc < 4; ++fc) {
          const int lc = lc0 + fc * 16;
          const float v = acc[i][fc][j] * sfac + lbias;
          const float uu = (tm + lr == tn + lc) ? -v : v;
          const float t = v * v;
          const float p = 0.69314718f +
              t * (0.125f +
              t * (-0.0052083335f +
              t * (0.00034722223f +
              t * (-2.6351686e-5f))));
          ls4[i] += mR * mC[fc] * (0.5f * uu + p);
        }
      }
    }
  } else {
    // exact fallback (not taken for bench scalars scale=1, bias=0)
#pragma unroll
    for (int i = 0; i < 4; ++i) {
#pragma unroll
      for (int j = 0; j < 4; ++j) {
        const int lr = lr0 + i * 16 + j;
        const float mR = shmask[lr];
#pragma unroll
        for (int fc = 0; fc < 4; ++fc) {
          const int lc = lc0 + fc * 16;
          const float v = acc[i][fc][j] * sfac + lbias;
          const float uu = (tm + lr == tn + lc) ? -v : v;
          const float loss =
              fmaxf(uu, 0.0f) + __logf(1.0f + __expf(-fabsf(uu)));
          ls4[i] += mR * mC[fc] * loss;
        }
      }
    }
  }
  float lsum = (ls4[0] + ls4[1]) + (ls4[2] + ls4[3]);

#pragma unroll
  for (int off = 32; off; off >>= 1) lsum += __shfl_down(lsum, off, 64);
  float* red = (float*)(sh + 2048);  // past shmask
  __syncthreads();
  if (lane == 0) red[wave] = lsum;
  __syncthreads();
  if (tid == 0)
    partial[g * 1024 + ty * 32 + tx] = red[0] + red[1] + red[2] + red[3];
}

// ---------------------------------------------------------------------------
// Kernel 3: fused finalize — 4 waves (one per group) + wave-0 combine.
// ---------------------------------------------------------------------------
__global__ __launch_bounds__(256) void finalize_kernel(
    const void* __restrict__ masks, const float* __restrict__ partial,
    float* __restrict__ out) {
  const int wv = threadIdx.x >> 6;   // group index
  const int lane = threadIdx.x & 63;
  const bool as_bytes = mask_is_bytes(masks);
  float cnt = 0.0f, ps = 0.0f;
  for (int i = lane; i < N_; i += 64)
    cnt += mask_val(masks, wv * N_ + i, as_bytes);
  for (int i = lane; i < 1024; i += 64) ps += partial[wv * 1024 + i];
#pragma unroll
  for (int off = 32; off; off >>= 1) {
    cnt += __shfl_down(cnt, off, 64);
    ps  += __shfl_down(ps,  off, 64);
  }
  __shared__ float rc[G_], rp[G_];
  if (lane == 0) { rc[wv] = cnt; rp[wv] = ps; }
  __syncthreads();
  if (threadIdx.x == 0) {
    float tot = 0.0f, nv = 0.0f;
#pragma unroll
    for (int g = 0; g < G_; ++g) {
      if (rc[g] > 0.0f) {
        tot += rp[g] / fmaxf(rc[g] * rc[g], 1.0f);
        nv += 1.0f;
      }
    }
    out[0] = tot / fmaxf(nv, 1.0f);
  }
}

// ---------------------------------------------------------------------------
extern "C" void kernel_launch(void* const* d_in, const int* in_sizes, int n_in,
                              void* d_out, int out_size, void* d_ws, size_t ws_size,
                              hipStream_t stream) {
  const float* merged = (const float*)d_in[0];
  const float* orig   = (const float*)d_in[1];
  const void*  masks  = (const void*)d_in[2];
  const float* ls     = (const float*)d_in[3];
  const float* lb     = (const float*)d_in[4];
  float* out = (float*)d_out;

  // ws: z1q [G*N*ROWB u8] | z2q | partial [G*1024 f32]
  unsigned char* z1q = (unsigned char*)d_ws;
  unsigned char* z2q = z1q + (size_t)G_ * N_ * ROWB_;
  float* partial = (float*)(z2q + (size_t)G_ * N_ * ROWB_);

  norm_kernel<<<2 * G_ * N_ / 4, 256, 0, stream>>>(merged, orig, z1q);
  gemm_loss_kernel<<<4096, 256, 0, stream>>>(z1q, z2q, masks, ls, lb, partial);
  finalize_kernel<<<1, 256, 0, stream>>>(masks, partial, out);
}

// Round 17
// 86.918 us; speedup vs baseline: 1.1726x; 1.1726x over previous
//
#include <hip/hip_runtime.h>
#include <hip/hip_bf16.h>
#include <stdint.h>

#define G_ 4
#define N_ 4096
#define D_ 1024             // K in elements
#define BKE_ 128            // K-elements per tile = one 16x16x128 fp4 MFMA
#define BKB_ 64             // K-bytes per tile row (fp4 = 0.5 B/elem)
#define KT_ (D_ / BKE_)     // 8 K-tiles
#define ROWB_ (D_ / 2)      // 512 B per row in fp4 z-file
#define MAX_LOGIT_SCALE_F 4.605170185988091f
#define ZS4 48.0f           // pre-quantization scale; logits /= ZS4^2

typedef float f32x4 __attribute__((ext_vector_type(4)));
typedef int i32x4 __attribute__((ext_vector_type(4)));
typedef int i32x8 __attribute__((ext_vector_type(8)));

#define AS1 __attribute__((address_space(1)))
#define AS3 __attribute__((address_space(3)))

// ---------------------------------------------------------------------------
// Mask dtype detection (reference dtype bool; harness may store bytes or i32).
// ---------------------------------------------------------------------------
__device__ inline bool mask_is_bytes(const void* masks) {
  const unsigned char* b = (const unsigned char*)masks;
  return (b[1] | b[2] | b[3]) != 0;
}
__device__ inline float mask_val(const void* masks, int idx, bool as_bytes) {
  if (as_bytes) return ((const unsigned char*)masks)[idx] ? 1.0f : 0.0f;
  return ((const int*)masks)[idx] ? 1.0f : 0.0f;
}

// ---------------------------------------------------------------------------
// fp4 e2m1 quantize (nearest; grid 0,.5,1,1.5,2,3,4,6) -> 4-bit code.
// ---------------------------------------------------------------------------
__device__ inline unsigned int q_e2m1(float x) {
  const unsigned int s = (__float_as_uint(x) >> 31) << 3;
  const float a = fabsf(x);
  unsigned int c;
  if (a < 1.25f) {
    c = (a < 0.25f) ? 0u : (a < 0.75f) ? 1u : 2u;
  } else if (a < 2.5f) {
    c = (a < 1.75f) ? 3u : 4u;
  } else {
    c = (a < 3.5f) ? 5u : (a < 5.0f) ? 6u : 7u;
  }
  return s | c;
}

// ---------------------------------------------------------------------------
// Kernel 1 (R10-verified): L2-normalize rows -> fp4 e2m1 pre-swizzled
// z-file. WAVE-per-row: lane holds 16 contiguous elems, __shfl_xor reduce,
// one u64 store. Swizzle: byte b -> (b&~63)|((b&63)^(((row>>1)&3)<<4)).
// ---------------------------------------------------------------------------
__global__ __launch_bounds__(256) void norm_kernel(
    const float* __restrict__ merged, const float* __restrict__ orig,
    unsigned char* __restrict__ zq) {
  const int w = threadIdx.x >> 6;
  const int lane = threadIdx.x & 63;
  const int row = blockIdx.x * 4 + w;         // 0 .. 2*G*N-1
  const int GN = G_ * N_;
  const float* src = (row < GN) ? (merged + (size_t)row * D_)
                                : (orig + (size_t)(row - GN) * D_);
  float4 v[4];
  float ss = 0.0f;
#pragma unroll
  for (int c = 0; c < 4; ++c) {
    v[c] = *reinterpret_cast<const float4*>(src + lane * 16 + c * 4);
    ss += v[c].x * v[c].x + v[c].y * v[c].y + v[c].z * v[c].z + v[c].w * v[c].w;
  }
#pragma unroll
  for (int off = 32; off; off >>= 1) ss += __shfl_xor(ss, off, 64);
  const float inv = ZS4 / fmaxf(sqrtf(ss), 1e-12f);

  unsigned long long pk = 0ull;
#pragma unroll
  for (int c = 0; c < 4; ++c) {
    pk |= (unsigned long long)q_e2m1(v[c].x * inv) << (c * 16 + 0);
    pk |= (unsigned long long)q_e2m1(v[c].y * inv) << (c * 16 + 4);
    pk |= (unsigned long long)q_e2m1(v[c].z * inv) << (c * 16 + 8);
    pk |= (unsigned long long)q_e2m1(v[c].w * inv) << (c * 16 + 12);
  }
  const int p0 = lane * 8;
  const int swz = ((row >> 1) & 3) << 4;
  const int off = (p0 & ~63) | ((p0 & 63) ^ swz);
  *reinterpret_cast<unsigned long long*>(zq + (size_t)row * ROWB_ + off) = pk;
}

// ---------------------------------------------------------------------------
// Kernel 2: 128x128-tile MX-fp4 GEMM + fused SigLIP loss. R8/R11 structure
// (#pragma unroll 1 load-bearing; launch_bounds(256,4) — 5 spills, R13).
// R15 config (best measured): cooperative mask staging — 2 coalesced
// loads/thread into LDS replace ~20 scattered global loads/thread.
// ---------------------------------------------------------------------------
__global__ __launch_bounds__(256, 4) void gemm_loss_kernel(
    const unsigned char* __restrict__ z1q, const unsigned char* __restrict__ z2q,
    const void* __restrict__ masks,
    const float* __restrict__ p_ls, const float* __restrict__ p_lb,
    float* __restrict__ partial) {
  // [buf][A 128x64 | B 128x64] = 2 * 16 KiB = 32 KiB exactly
  __shared__ __align__(16) unsigned char sh[2 * 16384];

  // 2D XCD-chunked swizzle: each XCD owns an 8x16 rect of a 32x32 tile grid.
  const int f   = blockIdx.x;          // 0..4095
  const int xcd = f & 7;
  const int u   = f >> 3;              // 0..511
  const int g   = u >> 7;              // 0..3
  const int q   = u & 127;             // 0..127
  const int ty  = (xcd >> 1) * 8 + (q >> 4);   // 0..31
  const int tx  = (xcd & 1) * 16 + (q & 15);   // 0..31
  const int tm = ty * 128;
  const int tn = tx * 128;

  const unsigned char* Abase = z1q + ((size_t)g * N_ + tm) * ROWB_;
  const unsigned char* Bbase = z2q + ((size_t)g * N_ + tn) * ROWB_;

  const int tid  = threadIdx.x;
  const int wave = tid >> 6;
  const int lane = tid & 63;
  const int wr = (wave >> 1) * 64;
  const int wc = (wave & 1) * 64;

  const int rlo  = lane & 15;
  const int kb0f = (lane >> 4) * 16;   // lane's 16-B (32-elem) K-chunk base

  f32x4 acc[4][4] = {};

  // hoisted loop-invariant swizzled LDS byte offsets (8 VGPR)
  int offA[4], offB[4];
#pragma unroll
  for (int i = 0; i < 4; ++i) {
    const int rowA = wr + i * 16 + rlo;
    offA[i] = rowA * BKB_ + (kb0f ^ (((rowA >> 1) & 3) << 4));
    const int rowB = wc + i * 16 + rlo;
    offB[i] = rowB * BKB_ + (kb0f ^ (((rowB >> 1) & 3) << 4));
  }

  // stage one 16-KB tile pair: 1024 granules of 16 B, 2 rounds x 256 thr
  // per operand. Dest wave-uniform (HW adds lane*16); source pre-swizzled.
  auto stage = [&](unsigned char* buf, int kt) {
    const int k0 = kt * BKB_;
#pragma unroll
    for (int r = 0; r < 2; ++r) {
      const int gr = r * 256 + tid;    // row = gr/4, granule = gr%4
      const unsigned char* sa =
          Abase + (size_t)(gr >> 2) * ROWB_ + k0 + (gr & 3) * 16;
      __builtin_amdgcn_global_load_lds(
          (const AS1 void*)sa, (AS3 void*)(buf + r * 4096 + wave * 1024),
          16, 0, 0);
      const unsigned char* sb =
          Bbase + (size_t)(gr >> 2) * ROWB_ + k0 + (gr & 3) * 16;
      __builtin_amdgcn_global_load_lds(
          (const AS1 void*)sb,
          (AS3 void*)(buf + 8192 + r * 4096 + wave * 1024), 16, 0, 0);
    }
  };

  auto read_frag = [&](const unsigned char* S, int off) -> i32x8 {
    const i32x4 lo = *reinterpret_cast<const i32x4*>(S + off);
    // fp4 FMT (cbsz/blgp=4) reads only v[0:3]; high half left undef.
    return __builtin_shufflevector(lo, lo, 0, 1, 2, 3, -1, -1, -1, -1);
  };

#define MFMA_FP4(a, b, c) \
  __builtin_amdgcn_mfma_scale_f32_16x16x128_f8f6f4((a), (b), (c), 4, 4, 0, 127, 0, 127)

  stage(sh, 0);
  __syncthreads();

#pragma unroll 1
  for (int kt = 0; kt < KT_; ++kt) {
    const unsigned char* bufR = sh + (kt & 1) * 16384;
    unsigned char* bufW = sh + ((kt + 1) & 1) * 16384;
    const unsigned char* sA = bufR;
    const unsigned char* sB = bufR + 8192;

    if (kt + 1 < KT_) stage(bufW, kt + 1);  // hides under this tile's MFMA

    i32x8 af[4];
#pragma unroll
    for (int i = 0; i < 4; ++i) af[i] = read_frag(sA, offA[i]);

#pragma unroll
    for (int j = 0; j < 4; ++j) {
      const i32x8 bfj = read_frag(sB, offB[j]);
#pragma unroll
      for (int i = 0; i < 4; ++i)
        acc[i][j] = MFMA_FP4(af[i], bfj, acc[i][j]);
    }
    __syncthreads();  // drains vmcnt (stage visible) + protects bufR
  }
#undef MFMA_FP4

  // ---- cooperative mask staging: 2 coalesced loads/thread -> LDS ----
  const bool as_bytes = mask_is_bytes(masks);
  const int mbase = g * N_;
  float* shmask = (float*)sh;  // 256 floats = 1 KB (tile reads all drained)
  {
    const int half = tid >> 7;          // 0: row masks, 1: col masks
    const int idx  = tid & 127;
    const int base = half ? (mbase + tn) : (mbase + tm);
    shmask[tid] = mask_val(masks, base + idx, as_bytes);
  }
  __syncthreads();

  // ---- fused loss epilogue (C/D layout shape-determined: m89/m127) ----
  const float scale = expf(fminf(p_ls[0], MAX_LOGIT_SCALE_F));
  const float sfac  = scale * (1.0f / (ZS4 * ZS4));
  const float lbias = p_lb[0];

  const int lr0 = wr + ((lane >> 4) << 2);  // local row base (+ i*16 + j)
  const int lc0 = wc + (lane & 15);         // local col base (+ fc*16)

  float mC[4];
#pragma unroll
  for (int fc = 0; fc < 4; ++fc) mC[fc] = shmask[128 + lc0 + fc * 16];

  float lsum = 0.0f;
  const bool poly_ok = (scale + fabsf(lbias) <= 1.5f);
  // softplus(u) = 0.5u + P(u^2), P = ln2 + t/8 - t^2/192 + t^3/2880
  //   - 17 t^4/645120; |u| <= scale*1.3 + |bias| (Cauchy-Schwarz + fp4 slack)
  if (poly_ok && tm != tn) {
    // off-diagonal block (97% of blocks): no r==c possible, u = +v always.
#pragma unroll
    for (int i = 0; i < 4; ++i) {
#pragma unroll
      for (int j = 0; j < 4; ++j) {
        const float mR = shmask[lr0 + i * 16 + j];
#pragma unroll
        for (int fc = 0; fc < 4; ++fc) {
          const float v = acc[i][fc][j] * sfac + lbias;  // logit = u
          const float t = v * v;
          const float p = 0.69314718f +
              t * (0.125f +
              t * (-0.0052083335f +
              t * (0.00034722223f +
              t * (-2.6351686e-5f))));
          lsum += mR * mC[fc] * (0.5f * v + p);
        }
      }
    }
  } else if (poly_ok) {
    // diagonal block: keep the r==c sign flip.
#pragma unroll
    for (int i = 0; i < 4; ++i) {
#pragma unroll
      for (int j = 0; j < 4; ++j) {
        const int lr = lr0 + i * 16 + j;
        const float mR = shmask[lr];
#pragma unroll
        for (int fc = 0; fc < 4; ++fc) {
          const int lc = lc0 + fc * 16;
          const float v = acc[i][fc][j] * sfac + lbias;
          const float uu = (tm + lr == tn + lc) ? -v : v;
          const float t = v * v;
          const float p = 0.69314718f +
              t * (0.125f +
              t * (-0.0052083335f +
              t * (0.00034722223f +
              t * (-2.6351686e-5f))));
          lsum += mR * mC[fc] * (0.5f * uu + p);
        }
      }
    }
  } else {
    // exact fallback (not taken for bench scalars scale=1, bias=0)
#pragma unroll
    for (int i = 0; i < 4; ++i) {
#pragma unroll
      for (int j = 0; j < 4; ++j) {
        const int lr = lr0 + i * 16 + j;
        const float mR = shmask[lr];
#pragma unroll
        for (int fc = 0; fc < 4; ++fc) {
          const int lc = lc0 + fc * 16;
          const float v = acc[i][fc][j] * sfac + lbias;
          const float uu = (tm + lr == tn + lc) ? -v : v;
          const float loss =
              fmaxf(uu, 0.0f) + __logf(1.0f + __expf(-fabsf(uu)));
          lsum += mR * mC[fc] * loss;
        }
      }
    }
  }

#pragma unroll
  for (int off = 32; off; off >>= 1) lsum += __shfl_down(lsum, off, 64);
  float* red = (float*)(sh + 2048);  // past shmask
  __syncthreads();
  if (lane == 0) red[wave] = lsum;
  __syncthreads();
  if (tid == 0)
    partial[g * 1024 + ty * 32 + tx] = red[0] + red[1] + red[2] + red[3];
}

// ---------------------------------------------------------------------------
// Kernel 3a: per-group n_sel + partial sum (one block per group).
// ---------------------------------------------------------------------------
__global__ __launch_bounds__(256) void finalize_pg(
    const void* __restrict__ masks, const float* __restrict__ partial,
    float* __restrict__ pg) {
  const int g = blockIdx.x;
  const int tid = threadIdx.x;
  const bool as_bytes = mask_is_bytes(masks);
  float cnt = 0.0f, ps = 0.0f;
  for (int i = tid; i < N_; i += 256) cnt += mask_val(masks, g * N_ + i, as_bytes);
  for (int i = tid; i < 1024; i += 256) ps += partial[g * 1024 + i];
#pragma unroll
  for (int off = 32; off; off >>= 1) {
    cnt += __shfl_down(cnt, off, 64);
    ps  += __shfl_down(ps,  off, 64);
  }
  __shared__ float rc[4], rp[4];
  if ((tid & 63) == 0) { rc[tid >> 6] = cnt; rp[tid >> 6] = ps; }
  __syncthreads();
  if (tid == 0) {
    pg[g * 2]     = rp[0] + rp[1] + rp[2] + rp[3];
    pg[g * 2 + 1] = rc[0] + rc[1] + rc[2] + rc[3];
  }
}

// ---------------------------------------------------------------------------
// Kernel 3b: combine 4 groups -> scalar.
// ---------------------------------------------------------------------------
__global__ void finalize2(const float* __restrict__ pg, float* __restrict__ out) {
  if (threadIdx.x == 0) {
    float tot = 0.0f, nv = 0.0f;
#pragma unroll
    for (int g = 0; g < G_; ++g) {
      const float ps = pg[g * 2];
      const float ns = pg[g * 2 + 1];
      if (ns > 0.0f) { tot += ps / fmaxf(ns * ns, 1.0f); nv += 1.0f; }
    }
    out[0] = tot / fmaxf(nv, 1.0f);
  }
}

// ---------------------------------------------------------------------------
extern "C" void kernel_launch(void* const* d_in, const int* in_sizes, int n_in,
                              void* d_out, int out_size, void* d_ws, size_t ws_size,
                              hipStream_t stream) {
  const float* merged = (const float*)d_in[0];
  const float* orig   = (const float*)d_in[1];
  const void*  masks  = (const void*)d_in[2];
  const float* ls     = (const float*)d_in[3];
  const float* lb     = (const float*)d_in[4];
  float* out = (float*)d_out;

  // ws: z1q [G*N*ROWB u8] | z2q | partial [G*1024 f32] | pg [8 f32]
  unsigned char* z1q = (unsigned char*)d_ws;
  unsigned char* z2q = z1q + (size_t)G_ * N_ * ROWB_;
  float* partial = (float*)(z2q + (size_t)G_ * N_ * ROWB_);
  float* pg = partial + G_ * 1024;

  norm_kernel<<<2 * G_ * N_ / 4, 256, 0, stream>>>(merged, orig, z1q);
  gemm_loss_kernel<<<4096, 256, 0, stream>>>(z1q, z2q, masks, ls, lb, partial);
  finalize_pg<<<G_, 256, 0, stream>>>(masks, partial, pg);
  finalize2<<<1, 64, 0, stream>>>(pg, out);
}